// Round 11
// baseline (695.446 us; speedup 1.0000x reference)
//
#include <hip/hip_runtime.h>

#define DD 1024
#define FF 4096
#define LL 24
#define VV 50277
#define NB 1024
#define AG __HIP_MEMORY_SCOPE_AGENT

typedef unsigned u32;
typedef float v4f __attribute__((ext_vector_type(4)));

// ---------------- reductions ----------------

__device__ __forceinline__ float wave_sum(float v) {
#pragma unroll
    for (int o = 32; o > 0; o >>= 1) v += __shfl_xor(v, o, 64);
    return v;
}

// single-pass LayerNorm over D=1024, 256-thread block
__device__ __forceinline__ v4f ln_fast(v4f x, const float* __restrict__ w,
                                       const float* __restrict__ b,
                                       float* scr, int t) {
    float s1 = x[0] + x[1] + x[2] + x[3];
    float s2 = x[0]*x[0] + x[1]*x[1] + x[2]*x[2] + x[3]*x[3];
    s1 = wave_sum(s1); s2 = wave_sum(s2);
    int wv = t >> 6;
    __syncthreads();
    if ((t & 63) == 0) { scr[wv] = s1; scr[4 + wv] = s2; }
    __syncthreads();
    float S1 = scr[0] + scr[1] + scr[2] + scr[3];
    float S2 = scr[4] + scr[5] + scr[6] + scr[7];
    float m = S1 * (1.0f / 1024.0f);
    float var = S2 * (1.0f / 1024.0f) - m * m;
    float rs = rsqrtf(var + 1e-5f);
    v4f w4 = ((const v4f*)w)[t], b4 = ((const v4f*)b)[t];
    return (x - m) * rs * w4 + b4;
}

__device__ __forceinline__ v4f mixv(v4f n, v4f s, v4f m) { return n * m + s * (1.0f - m); }

__device__ __forceinline__ float dotv(v4f a, v4f x) {
    return fmaf(a[0], x[0], fmaf(a[1], x[1], fmaf(a[2], x[2], a[3] * x[3])));
}

struct Row { v4f a, b, c, d; };

__device__ __forceinline__ void row_load(Row& r, const float* p, int lane) {
    const v4f* q = (const v4f*)p;
    r.a = q[lane]; r.b = q[lane + 64]; r.c = q[lane + 128]; r.d = q[lane + 192];
}
__device__ __forceinline__ void row_pin(Row& r) {
    asm volatile("" : "+v"(r.a), "+v"(r.b), "+v"(r.c), "+v"(r.d));
}
__device__ __forceinline__ float row_dot(const Row& r, const v4f* v, int lane) {
    return dotv(r.a, v[lane]) + dotv(r.b, v[lane + 64]) +
           dotv(r.c, v[lane + 128]) + dotv(r.d, v[lane + 192]);
}

// ---------------- coherent data ops (LLC, sc0sc1, relaxed agent) -----------

__device__ __forceinline__ void astore_f(float* p, float v) {
    __hip_atomic_store(p, v, __ATOMIC_RELAXED, AG);
}
__device__ __forceinline__ void cload(v4f& d, const float* p) {
    asm volatile("global_load_dwordx4 %0, %1, off sc0 sc1" : "=v"(d) : "v"(p));
}
__device__ __forceinline__ void cwait1(v4f& a) {
    asm volatile("s_waitcnt vmcnt(0)" : "+v"(a));
}
__device__ __forceinline__ void cwait4(v4f& a, v4f& b, v4f& c, v4f& d) {
    asm volatile("s_waitcnt vmcnt(0)" : "+v"(a), "+v"(b), "+v"(c), "+v"(d));
}

// ---------------- push-release grid barrier (r10, proven) ------------------

__device__ __forceinline__ void gbar(u32* sync, u32 ev, int b, int t) {
    __syncthreads();   // drains all waves' vmcnt: prefetch streams + data stores
    if (t == 0) {
        u32* shard = sync + (b & 7) * 32;
        u32* l2c   = sync + 8 * 32;
        u32* rel0  = sync + 9 * 32;
        u32 old = __hip_atomic_fetch_add(shard, 1u, __ATOMIC_RELAXED, AG);
        if (old == 128u * ev - 1u) {                 // shard-last
            u32 o2 = __hip_atomic_fetch_add(l2c, 1u, __ATOMIC_RELAXED, AG);
            if (o2 == 8u * ev - 1u) {                // global-last: push release
#pragma unroll
                for (int i = 0; i < 8; ++i)
                    __hip_atomic_store(rel0 + i * 32, ev, __ATOMIC_RELAXED, AG);
            }
        }
        u32* myrel = rel0 + (b & 7) * 32;
        while (__hip_atomic_load(myrel, __ATOMIC_RELAXED, AG) < ev)
            __builtin_amdgcn_s_sleep(2);
    }
    __syncthreads();
}

// ---------------- the whole network, one kernel ----------------
// 1024 blocks x 256 threads, 4 blocks/CU. Block b owns channel b of
// kw/vw/rw/ow/fvw/frw outputs and fkw rows 4b..4b+3. Each barrier window
// prefetches the NEXT stage's weight row into registers (one Row live at
// a time): gbar1<-fkw, gbar2<-frw quarter, gbar3<-fvw quarter, gbar4<-kvr/ow.

__global__ __launch_bounds__(256, 4) void rwkv_all(
    const float* __restrict__ token_embd, const float* __restrict__ state,
    const float* __restrict__ emb_ln_w, const float* __restrict__ emb_ln_b,
    const float* __restrict__ ln1_w, const float* __restrict__ ln1_b,
    const float* __restrict__ ln2_w, const float* __restrict__ ln2_b,
    const float* __restrict__ att_tmk, const float* __restrict__ att_tmv,
    const float* __restrict__ att_tmr, const float* __restrict__ att_tf,
    const float* __restrict__ att_td,
    const float* __restrict__ att_kw, const float* __restrict__ att_vw,
    const float* __restrict__ att_rw, const float* __restrict__ att_ow,
    const float* __restrict__ ffn_tmk, const float* __restrict__ ffn_tmr,
    const float* __restrict__ ffn_kw, const float* __restrict__ ffn_vw,
    const float* __restrict__ ffn_rw,
    const float* __restrict__ out_ln_w, const float* __restrict__ out_ln_b,
    const float* __restrict__ head_w,
    float* __restrict__ logits, float* __restrict__ st_out_base,
    float* __restrict__ ws, u32* __restrict__ sync) {

    __shared__ __align__(16) v4f s_buf[1024];   // 16 KB: mixes / k2 staging
    __shared__ __align__(16) v4f s_vec[256];    // 4 KB: rab / head vector
    __shared__ float scr[8];
    __shared__ float s_kvr[3];
    __shared__ float s_part[8];
    __shared__ float s_xsave;

    const int t = threadIdx.x, lane = t & 63, w = t >> 6, b = blockIdx.x;

    float* rab = ws;            // 1024
    float* xB  = ws + 1024;     // 1024
    float* k2  = ws + 2048;     // 4096
    float* xD  = ws + 6144;     // 1024

    // ---- prologue: start layer-0 kvr/ow streaming, then encoder LN -------
    Row rA;        // w0:kw[b] w1:vw[b] w2:rw[b] w3:ow[b]
    row_load(rA, (w == 0 ? att_kw : w == 1 ? att_vw : w == 2 ? att_rw : att_ow)
                 + (size_t)b * DD, lane);
    row_pin(rA);

    v4f xv = ((const v4f*)token_embd)[t];
    xv = ln_fast(xv, emb_ln_w, emb_ln_b, scr, t);

    u32 ev = 0;
#pragma unroll 1
    for (int i = 0; i < LL; ++i) {
        const size_t oD = (size_t)i * DD;
        const float* st = state + (size_t)i * 5 * DD;
        float* sto = st_out_base + (size_t)i * 5 * DD;
        const float scale = ((i + 1) % 6 == 0) ? 0.5f : 1.0f;

        // ===== stage A: LN1 + mix + {k,v,r} dots + in-block wkv ============
        if (i > 0) { cload(xv, xD + 4 * t); cwait1(xv); }
        if (t == (b >> 2)) s_xsave = xv[b & 3];          // x_in[b]
        v4f n = ln_fast(xv, ln1_w + oD, ln1_b + oD, scr, t);
        if (b == 0) ((v4f*)(sto + DD))[t] = n;           // new_st[1] = xn
        {
            v4f sa = ((const v4f*)(st + DD))[t];
            s_buf[t]       = mixv(n, sa, ((const v4f*)(att_tmk + oD))[t]);
            s_buf[256 + t] = mixv(n, sa, ((const v4f*)(att_tmv + oD))[t]);
            s_buf[512 + t] = mixv(n, sa, ((const v4f*)(att_tmr + oD))[t]);
        }
        __syncthreads();
        if (w < 3) {
            float acc = wave_sum(row_dot(rA, &s_buf[w * 256], lane));
            if (lane == 0) s_kvr[w] = acc;
        }
        __syncthreads();
        if (t == 0) {                                    // wkv for channel b
            float kk = s_kvr[0], vv = s_kvr[1];
            float rr = 1.0f / (1.0f + expf(-s_kvr[2]));
            float aa = st[2 * DD + b], bb = st[3 * DD + b], pp = st[4 * DD + b];
            float ww = att_tf[oD + b] + kk;
            float p = fmaxf(pp, ww);
            float e1 = expf(pp - p), e2 = expf(ww - p);
            astore_f(rab + b, rr * ((e1 * aa + e2 * vv) / (e1 * bb + e2)));
            float ww2 = pp + att_td[oD + b];
            float p2 = fmaxf(ww2, kk);
            float f1 = expf(ww2 - p2), f2 = expf(kk - p2);
            sto[2 * DD + b] = f1 * aa + f2 * vv;
            sto[3 * DD + b] = f1 * bb + f2;
            sto[4 * DD + b] = p2;
        }
        // prefetch fkw row 4b+w into the barrier window (kvr regs now dead,
        // w3's ow row rA stays live for stage B)
        Row rFK;
        row_load(rFK, ffn_kw + (size_t)i * FF * DD + (size_t)(4 * b + w) * DD, lane);
        row_pin(rFK);
        gbar(sync, ++ev, b, t);

        // ===== stage B: ow dot + residual ===================================
        { v4f rv; cload(rv, rab + 4 * t); cwait1(rv); s_vec[t] = rv; }
        __syncthreads();
        if (w == 3) {
            float acc = wave_sum(row_dot(rA, &s_vec[0], lane));
            if (lane == 0) astore_f(xB + b, s_xsave + acc);
        }
        // prefetch frw quarter (4 VGPRs) into the window
        v4f frq = ((const v4f*)(ffn_rw + (size_t)i * DD * DD + (size_t)b * DD))[w * 64 + lane];
        asm volatile("" : "+v"(frq));
        gbar(sync, ++ev, b, t);

        // ===== stage C: LN2 + mix + fkw rows (in regs) + frw quarters ======
        cload(xv, xB + 4 * t); cwait1(xv);
        if (t == (b >> 2)) s_xsave = xv[b & 3];          // x'[b]
        n = ln_fast(xv, ln2_w + oD, ln2_b + oD, scr, t);
        if (b == 0) ((v4f*)sto)[t] = n;                  // new_st[0] = xn2
        {
            v4f sf = ((const v4f*)st)[t];
            s_buf[t]       = mixv(n, sf, ((const v4f*)(ffn_tmk + oD))[t]);
            s_buf[256 + t] = mixv(n, sf, ((const v4f*)(ffn_tmr + oD))[t]);
        }
        __syncthreads();
        {
            float acc = wave_sum(row_dot(rFK, &s_buf[0], lane));
            if (lane == 0) { float rl = fmaxf(acc, 0.f); astore_f(k2 + 4 * b + w, rl * rl); }
            float pr = wave_sum(dotv(frq, s_buf[256 + w * 64 + lane]));
            if (lane == 0) s_part[w] = pr;               // frw partials (local)
        }
        // prefetch fvw quarter-row (fkw regs now dead)
        Row rFV;
        row_load(rFV, ffn_vw + (size_t)i * DD * FF + (size_t)b * FF + (size_t)w * 1024, lane);
        row_pin(rFV);
        gbar(sync, ++ev, b, t);

        // ===== stage D: fvw dot (in regs) + gated residual + rescale =======
        {
            v4f q0, q1, q2, q3;
            cload(q0, k2 + 4 * t);        cload(q1, k2 + 4 * t + 1024);
            cload(q2, k2 + 4 * t + 2048); cload(q3, k2 + 4 * t + 3072);
            cwait4(q0, q1, q2, q3);
            s_buf[t] = q0; s_buf[256 + t] = q1; s_buf[512 + t] = q2; s_buf[768 + t] = q3;
        }
        __syncthreads();
        {
            float acc = 0.f;
            acc += dotv(rFV.a, s_buf[w * 256 + lane]);
            acc += dotv(rFV.b, s_buf[w * 256 + lane + 64]);
            acc += dotv(rFV.c, s_buf[w * 256 + lane + 128]);
            acc += dotv(rFV.d, s_buf[w * 256 + lane + 192]);
            acc = wave_sum(acc);
            if (lane == 0) s_part[4 + w] = acc;
        }
        __syncthreads();
        if (t == 0) {
            float r2v = 1.0f / (1.0f + expf(-(s_part[0] + s_part[1] + s_part[2] + s_part[3])));
            float dsum = s_part[4] + s_part[5] + s_part[6] + s_part[7];
            astore_f(xD + b, (s_xsave + r2v * dsum) * scale);
        }
        // prefetch next layer's kvr/ow rows (fvw regs now dead)
        if (i + 1 < LL) {
            row_load(rA, (w == 0 ? att_kw : w == 1 ? att_vw : w == 2 ? att_rw : att_ow)
                         + (size_t)(i + 1) * DD * DD + (size_t)b * DD, lane);
            row_pin(rA);
        }
        gbar(sync, ++ev, b, t);
    }

    // ===== head: LN_out + 50277x1024 GEMV ==================================
    cload(xv, xD + 4 * t); cwait1(xv);
    v4f nh = ln_fast(xv, out_ln_w, out_ln_b, scr, t);
    s_vec[t] = nh;
    __syncthreads();
#pragma unroll 1
    for (int j = 0; j < 13; ++j) {
        int row = j * 4096 + 4 * b + w;
        if (row < VV) {
            Row rh;
            row_load(rh, head_w + (size_t)row * DD, lane);
            float acc = wave_sum(row_dot(rh, &s_vec[0], lane));
            if (lane == 0) logits[row] = acc;
        }
    }
}

// ---------------- launch ----------------

extern "C" void kernel_launch(void* const* d_in, const int* in_sizes, int n_in,
                              void* d_out, int out_size, void* d_ws, size_t ws_size,
                              hipStream_t stream) {
    const float* token_embd = (const float*)d_in[0];
    const float* state      = (const float*)d_in[1];
    const float* emb_ln_w   = (const float*)d_in[2];
    const float* emb_ln_b   = (const float*)d_in[3];
    const float* ln1_w      = (const float*)d_in[4];
    const float* ln1_b      = (const float*)d_in[5];
    const float* ln2_w      = (const float*)d_in[6];
    const float* ln2_b      = (const float*)d_in[7];
    const float* att_tmk    = (const float*)d_in[8];
    const float* att_tmv    = (const float*)d_in[9];
    const float* att_tmr    = (const float*)d_in[10];
    const float* att_tf     = (const float*)d_in[11];
    const float* att_td     = (const float*)d_in[12];
    const float* att_kw     = (const float*)d_in[13];
    const float* att_vw     = (const float*)d_in[14];
    const float* att_rw     = (const float*)d_in[15];
    const float* att_ow     = (const float*)d_in[16];
    const float* ffn_tmk    = (const float*)d_in[17];
    const float* ffn_tmr    = (const float*)d_in[18];
    const float* ffn_kw     = (const float*)d_in[19];
    const float* ffn_vw     = (const float*)d_in[20];
    const float* ffn_rw     = (const float*)d_in[21];
    const float* out_ln_w   = (const float*)d_in[22];
    const float* out_ln_b   = (const float*)d_in[23];
    const float* head_w     = (const float*)d_in[24];

    float* logits = (float*)d_out;
    float* st_out_base = (float*)d_out + VV;

    float* ws = (float*)d_ws;
    u32* sync = (u32*)(ws + 8192);      // 17 lines * 128 B

    hipMemsetAsync(sync, 0, 4096, stream);

    rwkv_all<<<NB, 256, 0, stream>>>(
        token_embd, state, emb_ln_w, emb_ln_b, ln1_w, ln1_b, ln2_w, ln2_b,
        att_tmk, att_tmv, att_tmr, att_tf, att_td,
        att_kw, att_vw, att_rw, att_ow,
        ffn_tmk, ffn_tmr, ffn_kw, ffn_vw, ffn_rw,
        out_ln_w, out_ln_b, head_w,
        logits, st_out_base, ws, sync);
}

// Round 12
// 582.940 us; speedup vs baseline: 1.1930x; 1.1930x over previous
//
#include <hip/hip_runtime.h>

#define DD 1024
#define FF 4096
#define LL 24
#define VV 50277

typedef float v4f __attribute__((ext_vector_type(4)));

// ---------------- reductions ----------------

__device__ __forceinline__ float wave_sum(float v) {
#pragma unroll
    for (int o = 32; o > 0; o >>= 1) v += __shfl_xor(v, o, 64);
    return v;
}

// single-pass LayerNorm over D=1024; NW waves in block, data on threads t<256
template <int NW>
__device__ __forceinline__ v4f ln_gen(v4f x, const float* __restrict__ w,
                                      const float* __restrict__ b,
                                      float* scr, int t, bool act) {
    float s1 = act ? (x[0] + x[1] + x[2] + x[3]) : 0.f;
    float s2 = act ? (x[0]*x[0] + x[1]*x[1] + x[2]*x[2] + x[3]*x[3]) : 0.f;
    s1 = wave_sum(s1); s2 = wave_sum(s2);
    int wv = t >> 6;
    __syncthreads();
    if ((t & 63) == 0) { scr[wv] = s1; scr[NW + wv] = s2; }
    __syncthreads();
    float S1 = 0.f, S2 = 0.f;
#pragma unroll
    for (int i = 0; i < NW; ++i) { S1 += scr[i]; S2 += scr[NW + i]; }
    float m = S1 * (1.0f / 1024.0f);
    float var = S2 * (1.0f / 1024.0f) - m * m;
    float rs = rsqrtf(var + 1e-5f);
    v4f w4 = act ? ((const v4f*)w)[t] : (v4f){0.f, 0.f, 0.f, 0.f};
    v4f b4 = act ? ((const v4f*)b)[t] : (v4f){0.f, 0.f, 0.f, 0.f};
    return (x - m) * rs * w4 + b4;
}

__device__ __forceinline__ v4f mixv(v4f n, v4f s, v4f m) { return n * m + s * (1.0f - m); }

__device__ __forceinline__ float dotv(v4f a, v4f x) {
    return fmaf(a[0], x[0], fmaf(a[1], x[1], fmaf(a[2], x[2], a[3] * x[3])));
}

struct Row { v4f a, b, c, d; };

__device__ __forceinline__ void row_load(Row& r, const float* p, int lane) {
    const v4f* q = (const v4f*)p;
    r.a = q[lane]; r.b = q[lane + 64]; r.c = q[lane + 128]; r.d = q[lane + 192];
}
__device__ __forceinline__ void row_pin(Row& r) {
    asm volatile("" : "+v"(r.a), "+v"(r.b), "+v"(r.c), "+v"(r.d));
}
__device__ __forceinline__ float row_dot(const Row& r, const v4f* v, int lane) {
    return dotv(r.a, v[lane]) + dotv(r.b, v[lane + 64]) +
           dotv(r.c, v[lane + 128]) + dotv(r.d, v[lane + 192]);
}

// ---------------- K1: [enc LN +] LN1 + mix + {k,v,r} rows + in-block wkv ----
// 256 blocks x 768 threads (12 waves). Block b owns channels 4b..4b+3.
// Wave w: matrix m=w>>2 (kw/vw/rw), channel 4b+(w&3). wkv is block-local.

__global__ __launch_bounds__(768) void k1_timemix(
    const float* __restrict__ xin, const float* __restrict__ st,
    const float* __restrict__ enc_w, const float* __restrict__ enc_b,
    const float* __restrict__ l1w, const float* __restrict__ l1b,
    const float* __restrict__ tmk, const float* __restrict__ tmv,
    const float* __restrict__ tmr, const float* __restrict__ tf,
    const float* __restrict__ td,
    const float* __restrict__ kw, const float* __restrict__ vw,
    const float* __restrict__ rw,
    float* __restrict__ rab, float* __restrict__ x0out, float* __restrict__ sto) {
    __shared__ __align__(16) v4f s_mix[3][256];
    __shared__ float kvrL[3][4];
    __shared__ float scr[24];
    const int t = threadIdx.x, lane = t & 63, w = t >> 6, b = blockIdx.x;

    // hoist weight row: streaming starts at t=0
    const int m = w >> 2, ch4 = w & 3;
    Row R;
    row_load(R, (m == 0 ? kw : m == 1 ? vw : rw) + (size_t)(4 * b + ch4) * DD, lane);
    row_pin(R);

    v4f xv = {0.f, 0.f, 0.f, 0.f};
    if (t < 256) xv = ((const v4f*)xin)[t];
    if (enc_w) xv = ln_gen<12>(xv, enc_w, enc_b, scr, t, t < 256);  // x0 = LN(emb)
    if (x0out && b == 0 && t < 256) ((v4f*)x0out)[t] = xv;          // publish x0
    v4f n = ln_gen<12>(xv, l1w, l1b, scr, t, t < 256);
    if (t < 256) {
        if (b == 0) ((v4f*)(sto + DD))[t] = n;                      // new_st[1]
        v4f sa = ((const v4f*)(st + DD))[t];
        s_mix[0][t] = mixv(n, sa, ((const v4f*)tmk)[t]);
        s_mix[1][t] = mixv(n, sa, ((const v4f*)tmv)[t]);
        s_mix[2][t] = mixv(n, sa, ((const v4f*)tmr)[t]);
    }
    __syncthreads();

    {   // 12 waves: one row each
        float acc = wave_sum(row_dot(R, &s_mix[m][0], lane));
        if (lane == 0) kvrL[m][ch4] = acc;
    }
    __syncthreads();

    if (t < 4) {   // wkv for own 4 channels — entirely block-local
        const int c = 4 * b + t;
        float kk = kvrL[0][t], vv = kvrL[1][t];
        float rr = 1.0f / (1.0f + expf(-kvrL[2][t]));
        float aa = st[2 * DD + c], bb = st[3 * DD + c], pp = st[4 * DD + c];
        float ww = tf[c] + kk;
        float p = fmaxf(pp, ww);
        float e1 = expf(pp - p), e2 = expf(ww - p);
        rab[c] = rr * ((e1 * aa + e2 * vv) / (e1 * bb + e2));
        float ww2 = pp + td[c];
        float p2 = fmaxf(ww2, kk);
        float f1 = expf(ww2 - p2), f2 = expf(kk - p2);
        sto[2 * DD + c] = f1 * aa + f2 * vv;
        sto[3 * DD + c] = f1 * bb + f2;
        sto[4 * DD + c] = p2;
    }
}

// ---------------- K2: ow GEMV + residual ------------------------------------
// 1024 blocks x 256 threads (4/CU, 16 waves/CU). Block r = ow row r;
// wave w covers columns [256w, 256w+256); rab staged in LDS.

__global__ __launch_bounds__(256) void k2_ow(
    const float* __restrict__ ow, const float* __restrict__ rab,
    float* __restrict__ x) {
    __shared__ __align__(16) v4f s_rab[256];
    __shared__ float s_part[4];
    const int t = threadIdx.x, lane = t & 63, w = t >> 6, r = blockIdx.x;

    // hoist weight chunk: one dwordx4 per thread
    v4f wv = *(const v4f*)(ow + (size_t)r * DD + 4 * t);
    asm volatile("" : "+v"(wv));

    s_rab[t] = ((const v4f*)rab)[t];
    __syncthreads();

    float acc = wave_sum(dotv(wv, s_rab[w * 64 + lane]));
    if (lane == 0) s_part[w] = acc;
    __syncthreads();
    if (t == 0)
        x[r] += s_part[0] + s_part[1] + s_part[2] + s_part[3];   // residual
}

// ---------------- K3: LN2 + chan-mix + {fkw,frw} GEMV (relu^2 / sigmoid) ----
// 1280 blocks (5120 rows) — unchanged from r9

__global__ __launch_bounds__(256) void k3_ffn_kr(
    const float* __restrict__ x, const float* __restrict__ st,
    const float* __restrict__ l2w, const float* __restrict__ l2b,
    const float* __restrict__ ftmk, const float* __restrict__ ftmr,
    const float* __restrict__ fkw, const float* __restrict__ frw,
    float* __restrict__ k2, float* __restrict__ r2, float* __restrict__ st_out) {
    __shared__ __align__(16) v4f s_k[256], s_r[256];
    __shared__ float scr[8];
    const int t = threadIdx.x, lane = t & 63, w = t >> 6, b = blockIdx.x;

    const int ridx = 4 * b + w;
    Row W;
    row_load(W, (ridx < FF ? fkw + (size_t)ridx * DD
                           : frw + (size_t)(ridx - FF) * DD), lane);
    row_pin(W);

    v4f xv = ((const v4f*)x)[t];
    v4f n = ln_gen<4>(xv, l2w, l2b, scr, t, true);
    if (b == 0) ((v4f*)st_out)[t] = n;                   // new_st[0] = xn2
    {
        v4f sf = ((const v4f*)st)[t];
        s_k[t] = mixv(n, sf, ((const v4f*)ftmk)[t]);
        s_r[t] = mixv(n, sf, ((const v4f*)ftmr)[t]);
    }
    __syncthreads();

    const v4f* vec = (ridx < FF) ? &s_k[0] : &s_r[0];
    float acc = wave_sum(row_dot(W, vec, lane));
    if (lane == 0) {
        if (ridx < FF) { float rl = fmaxf(acc, 0.f); k2[ridx] = rl * rl; }
        else           r2[ridx - FF] = 1.0f / (1.0f + expf(-acc));
    }
}

// ---------------- K4: fvw GEMV + gated residual + rescale -------------------
// 1024 blocks x 256 threads. Block r = fvw row r (4096 wide);
// wave w covers columns [1024w, 1024w+1024); k2 vector staged in LDS.

__global__ __launch_bounds__(256) void k4_ffn_v(
    const float* __restrict__ fvw, const float* __restrict__ k2,
    const float* __restrict__ r2, float* __restrict__ x, float scale) {
    __shared__ __align__(16) v4f k2s[1024];
    __shared__ float s_part[4];
    const int t = threadIdx.x, lane = t & 63, w = t >> 6, r = blockIdx.x;

    // hoist weight slice: 4 dwordx4 per thread (wave-contig at each j)
    const v4f* W4 = (const v4f*)(fvw + (size_t)r * FF) + (size_t)w * 256;
    v4f w0 = W4[lane], w1 = W4[lane + 64], w2 = W4[lane + 128], w3 = W4[lane + 192];
    asm volatile("" : "+v"(w0), "+v"(w1), "+v"(w2), "+v"(w3));

    // stage k2 vector (16 KB)
#pragma unroll
    for (int j = 0; j < 4; ++j)
        k2s[t + 256 * j] = ((const v4f*)k2)[t + 256 * j];
    __syncthreads();

    const v4f* kq = &k2s[w * 256];
    float acc = dotv(w0, kq[lane]) + dotv(w1, kq[lane + 64]) +
                dotv(w2, kq[lane + 128]) + dotv(w3, kq[lane + 192]);
    acc = wave_sum(acc);
    if (lane == 0) s_part[w] = acc;
    __syncthreads();
    if (t == 0) {
        float sum = s_part[0] + s_part[1] + s_part[2] + s_part[3];
        x[r] = (x[r] + r2[r] * sum) * scale;
    }
}

// ---------------- head: folded final LN + 50277x1024 GEMV -------------------

__global__ __launch_bounds__(256) void k_head(const float* __restrict__ head_w,
                                              const float* __restrict__ x,
                                              const float* __restrict__ olw,
                                              const float* __restrict__ olb,
                                              float* __restrict__ logits) {
    __shared__ __align__(16) v4f xs[256];
    __shared__ float scr[8];
    const int t = threadIdx.x, lane = t & 63, w = t >> 6;
    const int row = blockIdx.x * 4 + w;
    Row W;
    if (row < VV) { row_load(W, head_w + (size_t)row * DD, lane); row_pin(W); }

    v4f xv = ((const v4f*)x)[t];
    v4f nx = ln_gen<4>(xv, olw, olb, scr, t, true);
    xs[t] = nx;
    __syncthreads();
    if (row < VV) {
        float acc = wave_sum(row_dot(W, &xs[0], lane));
        if (lane == 0) logits[row] = acc;
    }
}

// ---------------- launch ----------------

extern "C" void kernel_launch(void* const* d_in, const int* in_sizes, int n_in,
                              void* d_out, int out_size, void* d_ws, size_t ws_size,
                              hipStream_t stream) {
    const float* token_embd = (const float*)d_in[0];
    const float* state      = (const float*)d_in[1];
    const float* emb_ln_w   = (const float*)d_in[2];
    const float* emb_ln_b   = (const float*)d_in[3];
    const float* ln1_w      = (const float*)d_in[4];
    const float* ln1_b      = (const float*)d_in[5];
    const float* ln2_w      = (const float*)d_in[6];
    const float* ln2_b      = (const float*)d_in[7];
    const float* att_tmk    = (const float*)d_in[8];
    const float* att_tmv    = (const float*)d_in[9];
    const float* att_tmr    = (const float*)d_in[10];
    const float* att_tf     = (const float*)d_in[11];
    const float* att_td     = (const float*)d_in[12];
    const float* att_kw     = (const float*)d_in[13];
    const float* att_vw     = (const float*)d_in[14];
    const float* att_rw     = (const float*)d_in[15];
    const float* att_ow     = (const float*)d_in[16];
    const float* ffn_tmk    = (const float*)d_in[17];
    const float* ffn_tmr    = (const float*)d_in[18];
    const float* ffn_kw     = (const float*)d_in[19];
    const float* ffn_vw     = (const float*)d_in[20];
    const float* ffn_rw     = (const float*)d_in[21];
    const float* out_ln_w   = (const float*)d_in[22];
    const float* out_ln_b   = (const float*)d_in[23];
    const float* head_w     = (const float*)d_in[24];

    float* logits = (float*)d_out;
    float* st_out_base = (float*)d_out + VV;

    float* ws   = (float*)d_ws;
    float* x    = ws;            // 1024
    float* rab  = ws + 1024;     // 1024
    float* k2b  = ws + 2048;     // 4096
    float* r2b  = ws + 6144;     // 1024

    for (int i = 0; i < LL; ++i) {
        const float* st = state + (size_t)i * 5 * DD;
        float* sto = st_out_base + (size_t)i * 5 * DD;

        k1_timemix<<<256, 768, 0, stream>>>(
            (i == 0) ? token_embd : x, st,
            (i == 0) ? emb_ln_w : nullptr, (i == 0) ? emb_ln_b : nullptr,
            ln1_w + i * DD, ln1_b + i * DD,
            att_tmk + i * DD, att_tmv + i * DD, att_tmr + i * DD,
            att_tf + i * DD, att_td + i * DD,
            att_kw + (size_t)i * DD * DD, att_vw + (size_t)i * DD * DD,
            att_rw + (size_t)i * DD * DD,
            rab, (i == 0) ? x : nullptr, sto);

        k2_ow<<<1024, 256, 0, stream>>>(
            att_ow + (size_t)i * DD * DD, rab, x);

        k3_ffn_kr<<<1280, 256, 0, stream>>>(
            x, st, ln2_w + i * DD, ln2_b + i * DD,
            ffn_tmk + i * DD, ffn_tmr + i * DD,
            ffn_kw + (size_t)i * FF * DD, ffn_rw + (size_t)i * DD * DD,
            k2b, r2b, sto);

        float scale = ((i + 1) % 6 == 0) ? 0.5f : 1.0f;
        k4_ffn_v<<<1024, 256, 0, stream>>>(
            ffn_vw + (size_t)i * DD * FF, k2b, r2b, x, scale);
    }

    k_head<<<(VV + 3) / 4, 256, 0, stream>>>(head_w, x, out_ln_w, out_ln_b, logits);
}